// Round 8
// baseline (244.852 us; speedup 1.0000x reference)
//
#include <hip/hip_runtime.h>

// out[n, t] = sum_{j <= t} W[t, j] * x[n, j] + b[t]
// B = 1048576, T = 32, fp32.
//
// R8 = R7 with the compile fix: __builtin_nontemporal_store requires a native
// vector type, not HIP's float4 class -> store through ext_vector_type(4).
// Theory (untested by R7): R0/R1/R2/R6 -- four structurally different kernels
// -- all pin at ~2.25-2.3 TB/s / ~89 us => memory service-rate wall.
// FETCH_SIZE = 65 MB for a 128 MB L3-resident input => the 128 MB output
// write-allocates in L3 each iter, evicting half the input (allocate/evict/
// refetch round-trips). Output is never re-read -> nt stores bypass L3
// allocation; input stays resident; writes stream to HBM.
//
// Structure (R6, verified): wave-private 8 KB LDS panels, zero s_barriers;
// global_load_lds w16 with pre-swizzled source; XOR-swizzled float4 layout;
// scalar-W triangular FMA (s_load -> SGPR operand).

constexpr int T    = 32;
constexpr int ROWS = 256;          // rows per block; 64 per wave

typedef float vfloat4 __attribute__((ext_vector_type(4)));

__global__ __launch_bounds__(256) void triu_kernel(
    const float* __restrict__ x, const float* __restrict__ W,
    const float* __restrict__ b, float* __restrict__ out)
{
    __shared__ float4 sX[ROWS * 8];    // 32 KiB; wave wid owns sX[wid*512 ..]

    const int tid  = threadIdx.x;
    const int lane = tid & 63;
    const int wid  = tid >> 6;

    const float4* __restrict__ x4 = reinterpret_cast<const float4*>(x);

    // This wave's 64-row panel (512 float4 = 8 KB).
    const long long wrow0 = (long long)blockIdx.x * ROWS + wid * 64;
    const float4*  __restrict__ src0 = x4 + wrow0 * 8;
    vfloat4*       __restrict__ dst0 = reinterpret_cast<vfloat4*>(out) + wrow0 * 8;
    float4* wlds = &sX[wid * 512];

    // Swizzled layout (R2-verified): chunk (row, c) of the panel lives at
    // slot row*8 + (c ^ (row&7)). global_load_lds writes linearly
    // (slot s = it*64 + lane), so the SOURCE is pre-swizzled:
    // s holds row = it*8 + (lane>>3), c = (lane&7) ^ (lane>>3).
    const int lrow = lane >> 3;                        // 0..7
    const int lsrc = lrow * 8 + ((lane & 7) ^ lrow);   // it-independent part

    #pragma unroll
    for (int it = 0; it < 8; ++it) {
        __builtin_amdgcn_global_load_lds(
            (const __attribute__((address_space(1))) void*)(src0 + it * 64 + lsrc),
            (__attribute__((address_space(3))) void*)(wlds + it * 64),
            16, 0, 0);
    }
    // Per-wave wait: loads' LDS writes retired when vmcnt hits 0. No barrier.
    asm volatile("s_waitcnt vmcnt(0)" ::: "memory");
    __builtin_amdgcn_sched_barrier(0);

    // Own row (row == lane of this wave's panel): 8 x ds_read_b128, XOR-inv.
    const int r7 = lane & 7;
    float xr[T];
    #pragma unroll
    for (int k = 0; k < 8; ++k) {
        const float4 v = wlds[lane * 8 + (k ^ r7)];
        xr[4*k+0] = v.x; xr[4*k+1] = v.y; xr[4*k+2] = v.z; xr[4*k+3] = v.w;
    }

    // Triangular FMA; W/b wave-uniform -> s_load + SGPR operand (R1-proven).
    float acc[T];
    #pragma unroll
    for (int t = 0; t < T; ++t) {
        float a = b[t];
        #pragma unroll
        for (int j = 0; j <= t; ++j)
            a = fmaf(W[t * T + j], xr[j], a);
        acc[t] = a;
    }

    // Writeback own row into the same swizzled slots.
    #pragma unroll
    for (int k = 0; k < 8; ++k)
        wlds[lane * 8 + (k ^ r7)] =
            make_float4(acc[4*k+0], acc[4*k+1], acc[4*k+2], acc[4*k+3]);

    // Wave-synchronous cross-lane handoff: all lanes executed the writes
    // above (program order), lgkmcnt(0) retires them; reads below are safe.
    asm volatile("s_waitcnt lgkmcnt(0)" ::: "memory");
    __builtin_amdgcn_sched_barrier(0);

    // Coalesced stage-out, NONTEMPORAL (global_store_dwordx4 ... nt):
    // bypass cache allocation for the write-once output stream so x stays
    // L3-resident. Out chunk idx = it*64+lane has row = it*8+lrow,
    // c = lane&7 -> swizzled slot = it*64 + lsrc (same formula as source).
    #pragma unroll
    for (int it = 0; it < 8; ++it) {
        const float4 v = wlds[it * 64 + lsrc];
        vfloat4 nv;
        nv.x = v.x; nv.y = v.y; nv.z = v.z; nv.w = v.w;
        __builtin_nontemporal_store(nv, dst0 + it * 64 + lane);
    }
}

extern "C" void kernel_launch(void* const* d_in, const int* in_sizes, int n_in,
                              void* d_out, int out_size, void* d_ws, size_t ws_size,
                              hipStream_t stream) {
    const float* x  = (const float*)d_in[0];   // [B, 32]
    const float* W  = (const float*)d_in[1];   // [32, 32] (lower-tri used)
    const float* b  = (const float*)d_in[2];   // [32]
    float* out      = (float*)d_out;           // [B, 32]

    const int batch = in_sizes[0] / T;         // 1048576
    const int grid  = batch / ROWS;            // 4096 blocks
    triu_kernel<<<grid, 256, 0, stream>>>(x, W, b, out);
}